// Round 11
// baseline (4401.936 us; speedup 1.0000x reference)
//
#include <hip/hip_runtime.h>
#include <hip/hip_fp16.h>
#include <cstdint>

typedef float f4 __attribute__((ext_vector_type(4)));
typedef _Float16 h2v __attribute__((ext_vector_type(2)));
typedef _Float16 half8 __attribute__((ext_vector_type(8)));
typedef unsigned long long u64;

// Problem constants
// B=32, F=34, T=1000, K=7, S=3, F_DOWN=10, C=64, H=640, 3H=1920, T_MAX=9, PAD=4, MS_KS=200

// ---------------------------------------------------------------------------
// K1: build DCLS kernel dk[h][i][tau], h<640, i<14, tau<9
__global__ void k_dk(const float* __restrict__ dcls_w, const float* __restrict__ dcls_p,
                     float* __restrict__ dk) {
    int idx = blockIdx.x * 256 + threadIdx.x;
    if (idx >= 640 * 126) return;
    int h = idx / 126;
    int r = idx % 126;
    int i = r / 9;
    int tau = r % 9;
    float p = dcls_p[h * 14 + i];
    p = fminf(fmaxf(p, 0.f), 8.f);
    float tri = fmaxf(1.f - fabsf((float)tau - p), 0.f);
    dk[idx] = dcls_w[h * 14 + i] * tri;
}

// ---------------------------------------------------------------------------
// K2: EMA lowpass (200-tap truncated, exact) + highpass. hp[b][f][t]
__global__ void k_ema(const float* __restrict__ x, const float* __restrict__ a_vals,
                      const float* __restrict__ w_vals, float* __restrict__ hp) {
    __shared__ float xr[1024];
    int bf = blockIdx.x;               // b*34+f
    int f = bf % 34;
    int tid = threadIdx.x;
    const float* xs = x + (size_t)bf * 1000;
    for (int i = tid; i < 1000; i += 256) xr[i] = xs[i];
    for (int i = 1000 + tid; i < 1024; i += 256) xr[i] = 0.f;
    __syncthreads();
    float a = a_vals[f], wv = w_vals[f];
    float om = 1.f - a;
    int t1 = tid, t2 = tid + 256, t3 = tid + 512, t4 = tid + 768;
    bool v4 = (t4 < 1000);
    float a0 = 0.f, a1 = 0.f, a2 = 0.f, a3 = 0.f;
    float coef = a;
    for (int k = 0; k < 200; ++k) {
        a0 += (k <= t1 ? xr[t1 - k] : 0.f) * coef;
        a1 += xr[t2 - k] * coef;
        a2 += xr[t3 - k] * coef;
        a3 += (v4 ? xr[t4 - k] : 0.f) * coef;
        coef *= om;
    }
    float* op = hp + (size_t)bf * 1000;
    op[t1] = xr[t1] - wv * a0;
    op[t2] = xr[t2] - wv * a1;
    op[t3] = xr[t3] - wv * a2;
    if (v4) op[t4] = xr[t4] - wv * a3;
}

// ---------------------------------------------------------------------------
// K3: DCLS grouped conv. ybcgt[b][h=c*10+g][t] = bias[g*64+c] + sum_{i,tau} u * dk
__global__ void __launch_bounds__(256) k_conv(const float* __restrict__ hp,
                                              const float* __restrict__ dk,
                                              const float* __restrict__ dcls_b,
                                              float* __restrict__ ybcgt) {
    __shared__ float u[2 * 7 * 264];    // [pm][kk][264]
    __shared__ float dks[64 * 126];
    int tid = threadIdx.x;
    int t0 = blockIdx.x * 256;
    int g = blockIdx.y;
    int b = blockIdx.z;
    for (int idx = tid; idx < 8064; idx += 256) dks[idx] = dk[g * 8064 + idx];
    for (int idx = tid; idx < 3696; idx += 256) {
        int pm = idx / 1848;
        int rem = idx % 1848;
        int kk = rem / 264;
        int tt = rem % 264;
        int tg = t0 - 4 + tt;
        float v = (tg >= 0 && tg < 1000) ? hp[((size_t)(b * 34 + g * 3 + kk)) * 1000 + tg] : 0.f;
        u[idx] = pm ? fmaxf(-v, 0.f) : fmaxf(v, 0.f);
    }
    __syncthreads();
    int tl = tid & 63;
    int cg4 = tid >> 6;     // 0..3, c = cg4*16+ci
    float acc[16][4];
#pragma unroll
    for (int ci = 0; ci < 16; ++ci)
#pragma unroll
        for (int tq = 0; tq < 4; ++tq) acc[ci][tq] = 0.f;

    for (int i = 0; i < 14; ++i) {
#pragma unroll
        for (int tau = 0; tau < 9; ++tau) {
            const float* ub = u + i * 264 + tl + tau;
            float u0 = ub[0];
            float u1 = ub[64];
            float u2 = ub[128];
            float u3 = ub[192];
            const float* dp = dks + cg4 * 16 * 126 + i * 9 + tau;
#pragma unroll
            for (int ci = 0; ci < 16; ++ci) {
                float dv = dp[ci * 126];
                acc[ci][0] += u0 * dv;
                acc[ci][1] += u1 * dv;
                acc[ci][2] += u2 * dv;
                acc[ci][3] += u3 * dv;
            }
        }
    }
#pragma unroll
    for (int ci = 0; ci < 16; ++ci) {
        int c = cg4 * 16 + ci;
        float bias = dcls_b[g * 64 + c];
        size_t base = ((size_t)(b * 640 + c * 10 + g)) * 1000;
#pragma unroll
        for (int tq = 0; tq < 4; ++tq) {
            int t = t0 + tq * 64 + tl;
            if (t < 1000) ybcgt[base + t] = acc[ci][tq] + bias;
        }
    }
}

// ---------------------------------------------------------------------------
// K4: BN stats: per channel c sum & sumsq over (b,g,t). bnsum[0..63]=sum, [64..127]=sumsq
__global__ void k_bnstat(const float* __restrict__ ybcgt, float* __restrict__ bnsum) {
    int c = blockIdx.x / 10;
    int g = blockIdx.x % 10;
    int tid = threadIdx.x;
    float s = 0.f, q = 0.f;
    const float* base = ybcgt + ((size_t)(c * 10 + g)) * 1000;
    for (int b = 0; b < 32; ++b) {
        const float* p = base + (size_t)b * 640000;
        for (int t = tid; t < 1000; t += 256) {
            float v = p[t];
            s += v;
            q += v * v;
        }
    }
    for (int off = 1; off < 64; off <<= 1) {
        s += __shfl_xor(s, off);
        q += __shfl_xor(q, off);
    }
    __shared__ float rs[4], rq[4];
    if ((tid & 63) == 0) { rs[tid >> 6] = s; rq[tid >> 6] = q; }
    __syncthreads();
    if (tid == 0) {
        s = rs[0] + rs[1] + rs[2] + rs[3];
        q = rq[0] + rq[1] + rq[2] + rq[3];
        atomicAdd(&bnsum[c], s);
        atomicAdd(&bnsum[64 + c], q);
    }
}

// K5: BN finalize -> bnp[c]=scale, bnp[64+c]=shift
__global__ void k_bnfin(const float* __restrict__ bnsum, const float* __restrict__ gamma,
                        const float* __restrict__ beta, float* __restrict__ bnp) {
    int c = threadIdx.x;
    const float inv_n = 1.f / 320000.f;
    float mean = bnsum[c] * inv_n;
    float var = bnsum[64 + c] * inv_n - mean * mean;
    float sc = gamma[c] * rsqrtf(var + 1e-5f);
    bnp[c] = sc;
    bnp[64 + c] = beta[c] - mean * sc;
}

// ---------------------------------------------------------------------------
// K6: fused transpose + BN + sigmoid: seq[(t*32+b)*640 + h] = sigmoid(scale*y + shift) (fp16)
__global__ void k_tr(const float* __restrict__ ybcgt, const float* __restrict__ bnp,
                     __half* __restrict__ seq) {
    __shared__ float tile[64 * 65];
    int tid = threadIdx.x;
    int tt0 = blockIdx.x * 64;
    int h0 = blockIdx.y * 64;
    int b = blockIdx.z;
    int tx = tid & 63;
    int ty = tid >> 6;
#pragma unroll
    for (int r = 0; r < 16; ++r) {
        int hh = r * 4 + ty;
        int t = tt0 + tx;
        float v = (t < 1000) ? ybcgt[((size_t)(b * 640 + h0 + hh)) * 1000 + t] : 0.f;
        int c = (h0 + hh) / 10;
        float sarg = bnp[c] * v + bnp[64 + c];
        tile[hh * 65 + tx] = 1.f / (1.f + __expf(-sarg));
    }
    __syncthreads();
#pragma unroll
    for (int r = 0; r < 16; ++r) {
        int t = tt0 + r * 4 + ty;
        if (t < 1000)
            seq[((size_t)t * 32 + b) * 640 + h0 + tx] = __float2half(tile[tx * 65 + r * 4 + ty]);
    }
}

// ---------------------------------------------------------------------------
// K7: x_proj GEMM (unchanged, passing)
#define BCOL(c) ((c) + (((c) >> 5) << 2))
__global__ void __launch_bounds__(256, 4) k_gemm(const __half* __restrict__ A,
                                                 const float* __restrict__ W,
                                                 const float* __restrict__ bih,
                                                 __half* __restrict__ C) {
    __shared__ float As[8][128];
    __shared__ float Bs[8][140];
    int tid = threadIdx.x;
    int n0 = blockIdx.x * 128;
    int m0 = blockIdx.y * 128;
    int tx = tid & 15;
    int ty = tid >> 4;
    int lm = tid >> 1;
    int lk4 = (tid & 1) * 4;
    int lmB = BCOL(lm);
    const int bc0 = BCOL(tx * 8);
    const int bc1 = BCOL(tx * 8 + 4);
    const __half* Ab = A + (size_t)(m0 + lm) * 640 + lk4;
    const float* Bb = W + (size_t)(n0 + lm) * 640 + lk4;

    f4 c0a = {0,0,0,0}, c0b = {0,0,0,0}, c1a = {0,0,0,0}, c1b = {0,0,0,0};
    f4 c2a = {0,0,0,0}, c2b = {0,0,0,0}, c3a = {0,0,0,0}, c3b = {0,0,0,0};
    f4 c4a = {0,0,0,0}, c4b = {0,0,0,0}, c5a = {0,0,0,0}, c5b = {0,0,0,0};
    f4 c6a = {0,0,0,0}, c6b = {0,0,0,0}, c7a = {0,0,0,0}, c7b = {0,0,0,0};

    for (int kt = 0; kt < 80; ++kt) {
        float2 araw = *(const float2*)(Ab + (size_t)kt * 8);
        const __half2* ah = (const __half2*)&araw;
        float2 a01 = __half22float2(ah[0]);
        float2 a23 = __half22float2(ah[1]);
        float4 bv = *(const float4*)(Bb + (size_t)kt * 8);
        __syncthreads();
        As[lk4 + 0][lm] = a01.x; As[lk4 + 1][lm] = a01.y;
        As[lk4 + 2][lm] = a23.x; As[lk4 + 3][lm] = a23.y;
        Bs[lk4 + 0][lmB] = bv.x; Bs[lk4 + 1][lmB] = bv.y;
        Bs[lk4 + 2][lmB] = bv.z; Bs[lk4 + 3][lmB] = bv.w;
        __syncthreads();
#pragma unroll
        for (int kk = 0; kk < 8; ++kk) {
            f4 blo = *(const f4*)&Bs[kk][bc0];
            f4 bhi = *(const f4*)&Bs[kk][bc1];
            f4 alo = *(const f4*)&As[kk][ty * 8];
            f4 ahi = *(const f4*)&As[kk][ty * 8 + 4];
            c0a += alo.x * blo; c0b += alo.x * bhi;
            c1a += alo.y * blo; c1b += alo.y * bhi;
            c2a += alo.z * blo; c2b += alo.z * bhi;
            c3a += alo.w * blo; c3b += alo.w * bhi;
            c4a += ahi.x * blo; c4b += ahi.x * bhi;
            c5a += ahi.y * blo; c5b += ahi.y * bhi;
            c6a += ahi.z * blo; c6b += ahi.z * bhi;
            c7a += ahi.w * blo; c7b += ahi.w * bhi;
        }
    }
    f4 bblo = *(const f4*)&bih[n0 + tx * 8];
    f4 bbhi = *(const f4*)&bih[n0 + tx * 8 + 4];
    union { __half h[8]; float4 v; } ob;
#define STORE_ROW(i, ra, rb)                                                     \
    {                                                                            \
        f4 lo = ra + bblo; f4 hi = rb + bbhi;                                    \
        ob.h[0] = __float2half(lo.x); ob.h[1] = __float2half(lo.y);              \
        ob.h[2] = __float2half(lo.z); ob.h[3] = __float2half(lo.w);              \
        ob.h[4] = __float2half(hi.x); ob.h[5] = __float2half(hi.y);              \
        ob.h[6] = __float2half(hi.z); ob.h[7] = __float2half(hi.w);              \
        *(float4*)&C[(size_t)(m0 + ty * 8 + i) * 1920 + n0 + tx * 8] = ob.v;     \
    }
    STORE_ROW(0, c0a, c0b) STORE_ROW(1, c1a, c1b) STORE_ROW(2, c2a, c2b)
    STORE_ROW(3, c3a, c3b) STORE_ROW(4, c4a, c4b) STORE_ROW(5, c5a, c5b)
    STORE_ROW(6, c6a, c6b) STORE_ROW(7, c7a, c7b)
#undef STORE_ROW
}

// ---------------------------------------------------------------------------
// K8 v9: XCD-local grouped MFMA GRU (v10 structure) + store-drain removal.
//  (1) In-loop barriers are lgkm-only (asm "s_waitcnt lgkmcnt(0); s_barrier"):
//      all in-loop barrier deps are LDS (staging->MFMA, red->epilogue, reuse
//      WAR); global publish/fcpart stores become fire-and-forget. __syncthreads
//      would drain vmcnt(0) = wait for the L3 slow publish every step.
//  (2) Publisher/spinner separation: waves 0-1 (epilogue+publish) never spin
//      or stage; waves 2-7 (clean vmcnt, no stores) take all 1280 exchange
//      entries (3-4 each). No thread's vmcnt(0) ever covers a pending store
//      (vmcnt retires in order -> a spin after stores would drain them).
//  (3) Slow publish via __hip_atomic_store (no return value -> no compiler
//      wait on register reuse; v5 proved equivalence).
// Tag-safety: own sc0 store in flight during own later spin just yields a
// stale (smaller) tag -> extra round, never falsely accepted (tags increase).
// Fallback to agent loads every 4th round keeps placement-independence.
__global__ void __launch_bounds__(512, 1) k_gru(const __half* __restrict__ xp,
                                                const float* __restrict__ Whh,
                                                const float* __restrict__ bhh,
                                                const float* __restrict__ fcw,
                                                u64* __restrict__ slowb,
                                                u64* __restrict__ fastb,
                                                float* __restrict__ fcpart) {
#define BARRIER() asm volatile("s_waitcnt lgkmcnt(0)\n\ts_barrier" ::: "memory")
    __shared__ __align__(16) h2v h_lds[16 * 324];     // [b(16, 4 real)][kp 320+pad]
    __shared__ __align__(16) float red[4 * 33 * 4];   // [b][j+pad][g+pad]
    __shared__ float fcred[2][4];

    const int tid = threadIdx.x;
    const int blk = blockIdx.x;
    const int grp = blk & 7;           // batch group (-> XCD if round-robin)
    const int sl = blk >> 3;           // j-slice 0..19
    const int lane = tid & 63;
    const int wid = tid >> 6;

    u64* const sbase = slowb + (size_t)grp * 2560;
    u64* const fbase = fastb + (size_t)grp * 2560;

    // ---- one-time: A-fragments (waves 0..5: gate=wid>>1, j-tile=wid&1) ----
    const int gte = wid >> 1, jt = wid & 1;
    half8 afrag[20];
    if (wid < 6) {
        int m = lane & 15;
        int kq = lane >> 4;
        const float* wrow = Whh + (size_t)(gte * 640 + sl * 32 + jt * 16 + m) * 640;
#pragma unroll
        for (int s = 0; s < 20; ++s) {
            float4 w0 = *(const float4*)&wrow[s * 32 + kq * 8];
            float4 w1 = *(const float4*)&wrow[s * 32 + kq * 8 + 4];
            afrag[s] = (half8){(_Float16)w0.x, (_Float16)w0.y, (_Float16)w0.z, (_Float16)w0.w,
                               (_Float16)w1.x, (_Float16)w1.y, (_Float16)w1.z, (_Float16)w1.w};
        }
    }
    // zero all of h_lds once (rows 4..15 stay zero forever -> B cols 4..15 = 0)
    for (int i = tid; i < 16 * 324; i += 512) h_lds[i] = (h2v){(_Float16)0.f, (_Float16)0.f};

    // spinner/stager mapping: waves 2..7 (384 threads) own the 1280 entries
    const int tp = tid - 128;                    // valid when tid >= 128
    const int E0 = tp, E1 = tp + 384, E2 = tp + 768;
    const bool h4 = (tp < 128);
    const int E3 = (tid >= 128 && h4) ? (1152 + tp) : E0;

    // epilogue mapping: tid<128 -> (j_local = tid>>2, b_local = tid&3)
    const int je = tid >> 2;
    const int be = tid & 3;
    float bh_r = 0.f, bh_z = 0.f, bh_n = 0.f, fw = 0.f, hold = 0.f;
    float xr = 0.f, xz = 0.f, xn = 0.f;
    if (tid < 128) {
        int jg = sl * 32 + je;
        bh_r = bhh[jg];
        bh_z = bhh[640 + jg];
        bh_n = bhh[1280 + jg];
        fw = fcw[jg];
        int bg = grp * 4 + be;
        const __half* xpt = xp + (size_t)bg * 1920;
        xr = __half2float(xpt[jg]);
        xz = __half2float(xpt[640 + jg]);
        xn = __half2float(xpt[1280 + jg]);
    }
    __syncthreads();   // full sync once: zeros + afrag loads done

    for (int t = 0; t < 1000; ++t) {
        u64* const scur = sbase + (size_t)(t & 1) * 1280;
        u64* const snxt = sbase + (size_t)((t + 1) & 1) * 1280;
        u64* const fcur = fbase + (size_t)(t & 1) * 1280;
        u64* const fnxt = fbase + (size_t)((t + 1) & 1) * 1280;

        // ---- spin+stage: waves 2..7 only (clean vmcnt) ----
        if (tid >= 128) {
            u64 v0 = 0, v1 = 0, v2 = 0, v3 = 0;
            bool g0 = false, g1 = false, g2 = false, g3 = !h4;
            const unsigned tg = (unsigned)t;
            int round = 0;
            for (;;) {
                u64 f0, f1, f2, f3;
                asm volatile(
                    "global_load_dwordx2 %0, %4, off sc0\n\t"
                    "global_load_dwordx2 %1, %5, off sc0\n\t"
                    "global_load_dwordx2 %2, %6, off sc0\n\t"
                    "global_load_dwordx2 %3, %7, off sc0\n\t"
                    "s_waitcnt vmcnt(0)"
                    : "=&v"(f0), "=&v"(f1), "=&v"(f2), "=&v"(f3)
                    : "v"(fcur + E0), "v"(fcur + E1), "v"(fcur + E2), "v"(fcur + E3)
                    : "memory");
                if (!g0 && (unsigned)(f0 >> 32) == tg) { v0 = f0; g0 = true; }
                if (!g1 && (unsigned)(f1 >> 32) == tg) { v1 = f1; g1 = true; }
                if (!g2 && (unsigned)(f2 >> 32) == tg) { v2 = f2; g2 = true; }
                if (!g3 && (unsigned)(f3 >> 32) == tg) { v3 = f3; g3 = true; }
                if (g0 & g1 & g2 & g3) break;
                if ((round & 3) == 2) {
                    if (!g0) {
                        u64 s0 = __hip_atomic_load(&scur[E0], __ATOMIC_RELAXED, __HIP_MEMORY_SCOPE_AGENT);
                        if ((unsigned)(s0 >> 32) == tg) { v0 = s0; g0 = true; }
                    }
                    if (!g1) {
                        u64 s1 = __hip_atomic_load(&scur[E1], __ATOMIC_RELAXED, __HIP_MEMORY_SCOPE_AGENT);
                        if ((unsigned)(s1 >> 32) == tg) { v1 = s1; g1 = true; }
                    }
                    if (!g2) {
                        u64 s2 = __hip_atomic_load(&scur[E2], __ATOMIC_RELAXED, __HIP_MEMORY_SCOPE_AGENT);
                        if ((unsigned)(s2 >> 32) == tg) { v2 = s2; g2 = true; }
                    }
                    if (!g3) {
                        u64 s3 = __hip_atomic_load(&scur[E3], __ATOMIC_RELAXED, __HIP_MEMORY_SCOPE_AGENT);
                        if ((unsigned)(s3 >> 32) == tg) { v3 = s3; g3 = true; }
                    }
                    if (g0 & g1 & g2 & g3) break;
                }
                __builtin_amdgcn_s_sleep(1);
                ++round;
            }
            // stage: entry e = kp*4 + b -> h_lds[b][kp]
            union { unsigned u; h2v h; } pk;
            pk.u = (unsigned)v0; h_lds[(E0 & 3) * 324 + (E0 >> 2)] = pk.h;
            pk.u = (unsigned)v1; h_lds[(E1 & 3) * 324 + (E1 >> 2)] = pk.h;
            pk.u = (unsigned)v2; h_lds[(E2 & 3) * 324 + (E2 >> 2)] = pk.h;
            if (h4) { pk.u = (unsigned)v3; h_lds[(E3 & 3) * 324 + (E3 >> 2)] = pk.h; }
        }
        BARRIER();   // S1: h staged (lgkm-only; publish stores keep draining)

        // prefetch xp for t+1 (overlaps MFMA; issued before publish stores so
        // its consumption wait never covers them)
        float nxr = 0.f, nxz = 0.f, nxn = 0.f;
        if (t + 1 < 1000 && tid < 128) {
            int jg = sl * 32 + je;
            int bg = grp * 4 + be;
            const __half* xpt = xp + ((size_t)(t + 1) * 32 + bg) * 1920;
            nxr = __half2float(xpt[jg]);
            nxz = __half2float(xpt[640 + jg]);
            nxn = __half2float(xpt[1280 + jg]);
        }

        // ---- MFMA: 6 waves, 20 k-steps ----
        if (wid < 6) {
            int bb = lane & 15;
            int kq = lane >> 4;
            const h2v* hb = &h_lds[bb * 324 + kq * 4];
            f4 acc = {0.f, 0.f, 0.f, 0.f};
#pragma unroll
            for (int s = 0; s < 20; ++s) {
                half8 bfrag = *(const half8*)&hb[s * 16];
                acc = __builtin_amdgcn_mfma_f32_16x16x32_f16(afrag[s], bfrag, acc, 0, 0, 0);
            }
            if (bb < 4) {
#pragma unroll
                for (int i = 0; i < 4; ++i)
                    red[(bb * 33 + jt * 16 + kq * 4 + i) * 4 + gte] = acc[i];
            }
        }
        BARRIER();   // S2: red ready

        // ---- epilogue: tid<128 = one (j,b) ----
        if (tid < 128) {
            f4 rv = *(const f4*)&red[(be * 33 + je) * 4];   // {r,z,n,pad}
            float hr = bh_r + rv.x;
            float hz = bh_z + rv.y;
            float hn = bh_n + rv.z;
            float r_ = 1.f / (1.f + __expf(-(xr + hr)));
            float z_ = 1.f / (1.f + __expf(-(xz + hz)));
            float pre = xn + r_ * hn;
            float e2v = __expf(-2.f * fabsf(pre));
            float tn = (1.f - e2v) / (1.f + e2v);
            float n_ = (pre >= 0.f) ? tn : -tn;
            float hnew = (1.f - z_) * n_ + z_ * hold;
            hold = hnew;
            // publish j-pair (even j holds {h[j], h[j+1]}); tid^4 = partner
            float hpair = __shfl_xor(hnew, 4);
            if ((je & 1) == 0) {
                union { h2v h2; unsigned u; } cv;
                cv.h2.x = (_Float16)hnew;
                cv.h2.y = (_Float16)hpair;
                u64 val = (u64)cv.u | ((u64)(unsigned)(t + 1) << 32);
                size_t eo = (size_t)((sl * 16 + (je >> 1)) * 4 + be);
                u64* fp = fnxt + eo;
                asm volatile("global_store_dwordx2 %0, %1, off sc0" :: "v"(fp), "v"(val) : "memory");
                __hip_atomic_store(snxt + eo, val,
                                   __ATOMIC_RELAXED, __HIP_MEMORY_SCOPE_AGENT);
            }
            // fc partial: reduce over this wave's 16 j (b preserved by xor 4,8,16,32)
            float fv = hnew * fw;
            fv += __shfl_xor(fv, 4);
            fv += __shfl_xor(fv, 8);
            fv += __shfl_xor(fv, 16);
            fv += __shfl_xor(fv, 32);
            if (lane < 4) fcred[wid][lane] = fv;
        }
        xr = nxr; xz = nxz; xn = nxn;
        BARRIER();   // S3: red/fcred consumed; h_lds free for next stage
        if (tid < 4)
            fcpart[(size_t)blk * 4000 + t * 4 + tid] = fcred[0][tid] + fcred[1][tid];
    }
#undef BARRIER
}

// ---------------------------------------------------------------------------
// K9: final fc: out[b*1000+t] = fc_b + sum over the 20 j-slices of group b/4
__global__ void k_fc(const float* __restrict__ fcpart, const float* __restrict__ fcb,
                     float* __restrict__ out) {
    int gid = blockIdx.x * 256 + threadIdx.x;  // < 32000
    int t = gid >> 5;
    int b = gid & 31;
    int g = b >> 2, bi = b & 3;
    float s = fcb[0];
    for (int sl = 0; sl < 20; ++sl)
        s += fcpart[(size_t)(g + 8 * sl) * 4000 + t * 4 + bi];
    out[(size_t)b * 1000 + t] = s;
}

// ---------------------------------------------------------------------------
extern "C" void kernel_launch(void* const* d_in, const int* in_sizes, int n_in,
                              void* d_out, int out_size, void* d_ws, size_t ws_size,
                              hipStream_t stream) {
    const float* x      = (const float*)d_in[0];
    const float* a_vals = (const float*)d_in[1];
    const float* w_vals = (const float*)d_in[2];
    const float* dcls_w = (const float*)d_in[3];
    const float* dcls_p = (const float*)d_in[4];
    const float* dcls_b = (const float*)d_in[5];
    const float* gamma  = (const float*)d_in[6];
    const float* beta   = (const float*)d_in[7];
    const float* W_ih   = (const float*)d_in[8];
    const float* W_hh   = (const float*)d_in[9];
    const float* b_ih   = (const float*)d_in[10];
    const float* b_hh   = (const float*)d_in[11];
    const float* fc_w   = (const float*)d_in[12];
    const float* fc_b   = (const float*)d_in[13];
    char* w = (char*)d_ws;

    // ws layout (bytes). Peak total: ~164.0 MB.
    //   [0, 122,880,000)           xpH   fp16 32000x1920  -- phase D
    //       overlay [0, 81,920,000)        ybcgt fp32     -- phases A-B (dead before GEMM)
    //   [122,880,000, 163,840,000) seqH  fp16 32000x640   -- phases B-C
    //       overlay phase D: fcpart fp32 160x4000 at 122,880,000 (2.56MB);
    //                        fastb  u64 8grp x 2 x 1280 at 125,440,000 (164KB)
    //       overlay phase A: hp fp32 + dk fp32
    //   [163,840,000, 164,003,840) slowb u64 8grp x 2 x 1280 (agent-scope exchange)
    //   [164,003,840, 164,004,352) bnsum fp32 128
    //   [164,004,352, 164,004,864) bnp   fp32 128
    //   [164,004,864, 164,006,912) bar   u32 (legacy, unused)
    __half* xpH    = (__half*)(w);
    float* ybcgt   = (float*)(w);
    __half* seqH   = (__half*)(w + 122880000);
    float* hp      = (float*)(w + 122880000);
    float* dk      = (float*)(w + 122880000 + 4352000);
    float* fcpart  = (float*)(w + 122880000);
    u64* fastb     = (u64*)(w + 125440000);
    u64* slowb     = (u64*)(w + 163840000);
    float* bnsum   = (float*)(w + 164003840);

    // zero slow exchange buffers (tag 0 = h(-1)=0) + bn accumulators + bnp + bar
    hipMemsetAsync(w + 163840000, 0, 166912, stream);

    k_dk<<<dim3(315), dim3(256), 0, stream>>>(dcls_w, dcls_p, dk);
    k_ema<<<dim3(1088), dim3(256), 0, stream>>>(x, a_vals, w_vals, hp);
    k_conv<<<dim3(4, 10, 32), dim3(256), 0, stream>>>(hp, dk, dcls_b, ybcgt);
    k_bnstat<<<dim3(640), dim3(256), 0, stream>>>(ybcgt, bnsum);
    k_bnfin<<<dim3(1), dim3(64), 0, stream>>>(bnsum, gamma, beta, (float*)(w + 164004352));
    k_tr<<<dim3(16, 10, 32), dim3(256), 0, stream>>>(ybcgt, (float*)(w + 164004352), seqH);
    k_gemm<<<dim3(15, 250), dim3(256), 0, stream>>>(seqH, W_ih, b_ih, xpH);

    // fast exchange buffer overlays (now-dead) seqH bytes: zero AFTER k_gemm
    hipMemsetAsync(w + 125440000, 0, 163840, stream);

    {
        const __half* xp_a = xpH;
        void* args[] = {(void*)&xp_a, (void*)&W_hh, (void*)&b_hh, (void*)&fc_w,
                        (void*)&slowb, (void*)&fastb, (void*)&fcpart};
        hipLaunchCooperativeKernel((void*)k_gru, dim3(160), dim3(512), args, 0, stream);
    }

    k_fc<<<dim3(125), dim3(256), 0, stream>>>(fcpart, fc_b, (float*)d_out);
}

// Round 12
// 3450.524 us; speedup vs baseline: 1.2757x; 1.2757x over previous
//
#include <hip/hip_runtime.h>
#include <hip/hip_fp16.h>
#include <cstdint>

typedef float f4 __attribute__((ext_vector_type(4)));
typedef _Float16 h2v __attribute__((ext_vector_type(2)));
typedef _Float16 half8 __attribute__((ext_vector_type(8)));
typedef unsigned long long u64;

// Problem constants
// B=32, F=34, T=1000, K=7, S=3, F_DOWN=10, C=64, H=640, 3H=1920, T_MAX=9, PAD=4, MS_KS=200

// ---------------------------------------------------------------------------
// K1: build DCLS kernel dk[h][i][tau], h<640, i<14, tau<9
__global__ void k_dk(const float* __restrict__ dcls_w, const float* __restrict__ dcls_p,
                     float* __restrict__ dk) {
    int idx = blockIdx.x * 256 + threadIdx.x;
    if (idx >= 640 * 126) return;
    int h = idx / 126;
    int r = idx % 126;
    int i = r / 9;
    int tau = r % 9;
    float p = dcls_p[h * 14 + i];
    p = fminf(fmaxf(p, 0.f), 8.f);
    float tri = fmaxf(1.f - fabsf((float)tau - p), 0.f);
    dk[idx] = dcls_w[h * 14 + i] * tri;
}

// ---------------------------------------------------------------------------
// K2: EMA lowpass (200-tap truncated, exact) + highpass. hp[b][f][t]
__global__ void k_ema(const float* __restrict__ x, const float* __restrict__ a_vals,
                      const float* __restrict__ w_vals, float* __restrict__ hp) {
    __shared__ float xr[1024];
    int bf = blockIdx.x;               // b*34+f
    int f = bf % 34;
    int tid = threadIdx.x;
    const float* xs = x + (size_t)bf * 1000;
    for (int i = tid; i < 1000; i += 256) xr[i] = xs[i];
    for (int i = 1000 + tid; i < 1024; i += 256) xr[i] = 0.f;
    __syncthreads();
    float a = a_vals[f], wv = w_vals[f];
    float om = 1.f - a;
    int t1 = tid, t2 = tid + 256, t3 = tid + 512, t4 = tid + 768;
    bool v4 = (t4 < 1000);
    float a0 = 0.f, a1 = 0.f, a2 = 0.f, a3 = 0.f;
    float coef = a;
    for (int k = 0; k < 200; ++k) {
        a0 += (k <= t1 ? xr[t1 - k] : 0.f) * coef;
        a1 += xr[t2 - k] * coef;
        a2 += xr[t3 - k] * coef;
        a3 += (v4 ? xr[t4 - k] : 0.f) * coef;
        coef *= om;
    }
    float* op = hp + (size_t)bf * 1000;
    op[t1] = xr[t1] - wv * a0;
    op[t2] = xr[t2] - wv * a1;
    op[t3] = xr[t3] - wv * a2;
    if (v4) op[t4] = xr[t4] - wv * a3;
}

// ---------------------------------------------------------------------------
// K3: DCLS grouped conv. ybcgt[b][h=c*10+g][t] = bias[g*64+c] + sum_{i,tau} u * dk
__global__ void __launch_bounds__(256) k_conv(const float* __restrict__ hp,
                                              const float* __restrict__ dk,
                                              const float* __restrict__ dcls_b,
                                              float* __restrict__ ybcgt) {
    __shared__ float u[2 * 7 * 264];    // [pm][kk][264]
    __shared__ float dks[64 * 126];
    int tid = threadIdx.x;
    int t0 = blockIdx.x * 256;
    int g = blockIdx.y;
    int b = blockIdx.z;
    for (int idx = tid; idx < 8064; idx += 256) dks[idx] = dk[g * 8064 + idx];
    for (int idx = tid; idx < 3696; idx += 256) {
        int pm = idx / 1848;
        int rem = idx % 1848;
        int kk = rem / 264;
        int tt = rem % 264;
        int tg = t0 - 4 + tt;
        float v = (tg >= 0 && tg < 1000) ? hp[((size_t)(b * 34 + g * 3 + kk)) * 1000 + tg] : 0.f;
        u[idx] = pm ? fmaxf(-v, 0.f) : fmaxf(v, 0.f);
    }
    __syncthreads();
    int tl = tid & 63;
    int cg4 = tid >> 6;     // 0..3, c = cg4*16+ci
    float acc[16][4];
#pragma unroll
    for (int ci = 0; ci < 16; ++ci)
#pragma unroll
        for (int tq = 0; tq < 4; ++tq) acc[ci][tq] = 0.f;

    for (int i = 0; i < 14; ++i) {
#pragma unroll
        for (int tau = 0; tau < 9; ++tau) {
            const float* ub = u + i * 264 + tl + tau;
            float u0 = ub[0];
            float u1 = ub[64];
            float u2 = ub[128];
            float u3 = ub[192];
            const float* dp = dks + cg4 * 16 * 126 + i * 9 + tau;
#pragma unroll
            for (int ci = 0; ci < 16; ++ci) {
                float dv = dp[ci * 126];
                acc[ci][0] += u0 * dv;
                acc[ci][1] += u1 * dv;
                acc[ci][2] += u2 * dv;
                acc[ci][3] += u3 * dv;
            }
        }
    }
#pragma unroll
    for (int ci = 0; ci < 16; ++ci) {
        int c = cg4 * 16 + ci;
        float bias = dcls_b[g * 64 + c];
        size_t base = ((size_t)(b * 640 + c * 10 + g)) * 1000;
#pragma unroll
        for (int tq = 0; tq < 4; ++tq) {
            int t = t0 + tq * 64 + tl;
            if (t < 1000) ybcgt[base + t] = acc[ci][tq] + bias;
        }
    }
}

// ---------------------------------------------------------------------------
// K4: BN stats: per channel c sum & sumsq over (b,g,t). bnsum[0..63]=sum, [64..127]=sumsq
__global__ void k_bnstat(const float* __restrict__ ybcgt, float* __restrict__ bnsum) {
    int c = blockIdx.x / 10;
    int g = blockIdx.x % 10;
    int tid = threadIdx.x;
    float s = 0.f, q = 0.f;
    const float* base = ybcgt + ((size_t)(c * 10 + g)) * 1000;
    for (int b = 0; b < 32; ++b) {
        const float* p = base + (size_t)b * 640000;
        for (int t = tid; t < 1000; t += 256) {
            float v = p[t];
            s += v;
            q += v * v;
        }
    }
    for (int off = 1; off < 64; off <<= 1) {
        s += __shfl_xor(s, off);
        q += __shfl_xor(q, off);
    }
    __shared__ float rs[4], rq[4];
    if ((tid & 63) == 0) { rs[tid >> 6] = s; rq[tid >> 6] = q; }
    __syncthreads();
    if (tid == 0) {
        s = rs[0] + rs[1] + rs[2] + rs[3];
        q = rq[0] + rq[1] + rq[2] + rq[3];
        atomicAdd(&bnsum[c], s);
        atomicAdd(&bnsum[64 + c], q);
    }
}

// K5: BN finalize -> bnp[c]=scale, bnp[64+c]=shift
__global__ void k_bnfin(const float* __restrict__ bnsum, const float* __restrict__ gamma,
                        const float* __restrict__ beta, float* __restrict__ bnp) {
    int c = threadIdx.x;
    const float inv_n = 1.f / 320000.f;
    float mean = bnsum[c] * inv_n;
    float var = bnsum[64 + c] * inv_n - mean * mean;
    float sc = gamma[c] * rsqrtf(var + 1e-5f);
    bnp[c] = sc;
    bnp[64 + c] = beta[c] - mean * sc;
}

// ---------------------------------------------------------------------------
// K6: fused transpose + BN + sigmoid: seq[(t*32+b)*640 + h] = sigmoid(scale*y + shift) (fp16)
__global__ void k_tr(const float* __restrict__ ybcgt, const float* __restrict__ bnp,
                     __half* __restrict__ seq) {
    __shared__ float tile[64 * 65];
    int tid = threadIdx.x;
    int tt0 = blockIdx.x * 64;
    int h0 = blockIdx.y * 64;
    int b = blockIdx.z;
    int tx = tid & 63;
    int ty = tid >> 6;
#pragma unroll
    for (int r = 0; r < 16; ++r) {
        int hh = r * 4 + ty;
        int t = tt0 + tx;
        float v = (t < 1000) ? ybcgt[((size_t)(b * 640 + h0 + hh)) * 1000 + t] : 0.f;
        int c = (h0 + hh) / 10;
        float sarg = bnp[c] * v + bnp[64 + c];
        tile[hh * 65 + tx] = 1.f / (1.f + __expf(-sarg));
    }
    __syncthreads();
#pragma unroll
    for (int r = 0; r < 16; ++r) {
        int t = tt0 + r * 4 + ty;
        if (t < 1000)
            seq[((size_t)t * 32 + b) * 640 + h0 + tx] = __float2half(tile[tx * 65 + r * 4 + ty]);
    }
}

// ---------------------------------------------------------------------------
// K7 v2: x_proj GEMM via MFMA fp16. C[32000][1920] = A[32000][640] x W^T + b.
// A = seqH fp16 (row-major [m][k]); W fp32 [n][k] (B^T form), cast fp16 at
// staging (quantization ~5e-4 on x_proj, below xpH's own fp16 rounding).
// BM=BN=128, BK=32, 256 thr = 4 waves; wave owns 64x64 (4x4 16x16 frags,
// 16 MFMA/kstep, 20 ksteps). LDS [128][40] fp16 (stride-40 pad -> 2-way
// banks = free). Fragment mapping = k_gru's verified one:
// A-frag lane: m=lane&15, k=kq*8+i (kq=lane>>4); C: col(n)=lane&15,
// row(m)=kq*4+reg. A and B share the slot->k map (permutation cancels).
__global__ void __launch_bounds__(256, 2) k_gemm(const __half* __restrict__ A,
                                                 const float* __restrict__ W,
                                                 const float* __restrict__ bih,
                                                 __half* __restrict__ C) {
    __shared__ __align__(16) _Float16 As[128 * 40];
    __shared__ __align__(16) _Float16 Bs[128 * 40];
    const int tid = threadIdx.x;
    const int n0 = blockIdx.x * 128;
    const int m0 = blockIdx.y * 128;
    const int lane = tid & 63;
    const int wid = tid >> 6;          // 0..3
    const int ml = lane & 15;
    const int kq = lane >> 4;          // 0..3
    const int wm = (wid & 1) * 64;
    const int wn = (wid >> 1) * 64;
    const int sr = tid >> 1;           // staging row 0..127
    const int sc = (tid & 1) * 16;     // staging col (halves/floats)

    f4 acc[4][4];
#pragma unroll
    for (int mt = 0; mt < 4; ++mt)
#pragma unroll
        for (int nt = 0; nt < 4; ++nt) acc[mt][nt] = (f4){0.f, 0.f, 0.f, 0.f};

    const __half* Ag = A + (size_t)(m0 + sr) * 640 + sc;
    const float* Wg = W + (size_t)(n0 + sr) * 640 + sc;

    for (int s = 0; s < 20; ++s) {
        const int k0 = s * 32;
        half8 a0 = *(const half8*)(Ag + k0);
        half8 a1 = *(const half8*)(Ag + k0 + 8);
        float4 b0 = *(const float4*)(Wg + k0);
        float4 b1 = *(const float4*)(Wg + k0 + 4);
        float4 b2 = *(const float4*)(Wg + k0 + 8);
        float4 b3 = *(const float4*)(Wg + k0 + 12);
        __syncthreads();   // previous iteration's frag reads done (WAR)
        *(half8*)&As[sr * 40 + sc] = a0;
        *(half8*)&As[sr * 40 + sc + 8] = a1;
        half8 bh0 = {(_Float16)b0.x, (_Float16)b0.y, (_Float16)b0.z, (_Float16)b0.w,
                     (_Float16)b1.x, (_Float16)b1.y, (_Float16)b1.z, (_Float16)b1.w};
        half8 bh1 = {(_Float16)b2.x, (_Float16)b2.y, (_Float16)b2.z, (_Float16)b2.w,
                     (_Float16)b3.x, (_Float16)b3.y, (_Float16)b3.z, (_Float16)b3.w};
        *(half8*)&Bs[sr * 40 + sc] = bh0;
        *(half8*)&Bs[sr * 40 + sc + 8] = bh1;
        __syncthreads();   // tile staged
        half8 af[4], bf[4];
#pragma unroll
        for (int mt = 0; mt < 4; ++mt)
            af[mt] = *(const half8*)&As[(wm + mt * 16 + ml) * 40 + kq * 8];
#pragma unroll
        for (int nt = 0; nt < 4; ++nt)
            bf[nt] = *(const half8*)&Bs[(wn + nt * 16 + ml) * 40 + kq * 8];
#pragma unroll
        for (int mt = 0; mt < 4; ++mt)
#pragma unroll
            for (int nt = 0; nt < 4; ++nt)
                acc[mt][nt] = __builtin_amdgcn_mfma_f32_16x16x32_f16(af[mt], bf[nt],
                                                                     acc[mt][nt], 0, 0, 0);
    }
    // epilogue: C[m][n] = acc + bih[n], fp16
#pragma unroll
    for (int nt = 0; nt < 4; ++nt) {
        int n = n0 + wn + nt * 16 + ml;
        float bias = bih[n];
#pragma unroll
        for (int mt = 0; mt < 4; ++mt) {
            int mbase = m0 + wm + mt * 16 + kq * 4;
#pragma unroll
            for (int i = 0; i < 4; ++i)
                C[(size_t)(mbase + i) * 1920 + n] = __float2half(acc[mt][nt][i] + bias);
        }
    }
}

// ---------------------------------------------------------------------------
// K8 v10 (EXACT round-10 kernel, measured 3080us steady, passed):
// XCD-local grouped MFMA GRU. 8 groups x 4 batches; group = blockIdx & 7.
// 20 blocks x 32 j-rows per group; exchange is group-local. Double publish:
// fast sc0 (L2) + slow agent swap (L3 insurance); spin on sc0 loads with
// agent fallback every 4th round.
__global__ void __launch_bounds__(512, 1) k_gru(const __half* __restrict__ xp,
                                                const float* __restrict__ Whh,
                                                const float* __restrict__ bhh,
                                                const float* __restrict__ fcw,
                                                u64* __restrict__ slowb,
                                                u64* __restrict__ fastb,
                                                float* __restrict__ fcpart) {
    __shared__ __align__(16) h2v h_lds[16 * 324];     // [b(16, 4 real)][kp 320+pad]
    __shared__ __align__(16) float red[4 * 33 * 4];   // [b][j+pad][g+pad]
    __shared__ float fcred[2][4];

    const int tid = threadIdx.x;
    const int blk = blockIdx.x;
    const int grp = blk & 7;           // batch group (-> XCD if round-robin)
    const int sl = blk >> 3;           // j-slice 0..19
    const int lane = tid & 63;
    const int wid = tid >> 6;

    u64* const sbase = slowb + (size_t)grp * 2560;
    u64* const fbase = fastb + (size_t)grp * 2560;

    // ---- one-time: A-fragments (waves 0..5: gate=wid>>1, j-tile=wid&1) ----
    const int gte = wid >> 1, jt = wid & 1;
    half8 afrag[20];
    if (wid < 6) {
        int m = lane & 15;
        int kq = lane >> 4;
        const float* wrow = Whh + (size_t)(gte * 640 + sl * 32 + jt * 16 + m) * 640;
#pragma unroll
        for (int s = 0; s < 20; ++s) {
            float4 w0 = *(const float4*)&wrow[s * 32 + kq * 8];
            float4 w1 = *(const float4*)&wrow[s * 32 + kq * 8 + 4];
            afrag[s] = (half8){(_Float16)w0.x, (_Float16)w0.y, (_Float16)w0.z, (_Float16)w0.w,
                               (_Float16)w1.x, (_Float16)w1.y, (_Float16)w1.z, (_Float16)w1.w};
        }
    }
    // zero all of h_lds once (rows 4..15 stay zero forever -> B cols 4..15 = 0)
    for (int i = tid; i < 16 * 324; i += 512) h_lds[i] = (h2v){(_Float16)0.f, (_Float16)0.f};

    // per-thread exchange entries
    const int e0 = tid, e1 = tid + 512;
    const bool has3 = (tid < 256);
    const int e2 = has3 ? tid + 1024 : tid;

    // epilogue mapping: tid<128 -> (j_local = tid>>2, b_local = tid&3)
    const int je = tid >> 2;
    const int be = tid & 3;
    float bh_r = 0.f, bh_z = 0.f, bh_n = 0.f, fw = 0.f, hold = 0.f;
    float xr = 0.f, xz = 0.f, xn = 0.f;
    if (tid < 128) {
        int jg = sl * 32 + je;
        bh_r = bhh[jg];
        bh_z = bhh[640 + jg];
        bh_n = bhh[1280 + jg];
        fw = fcw[jg];
        int bg = grp * 4 + be;
        const __half* xpt = xp + (size_t)bg * 1920;
        xr = __half2float(xpt[jg]);
        xz = __half2float(xpt[640 + jg]);
        xn = __half2float(xpt[1280 + jg]);
    }
    __syncthreads();   // zeros done before first staging writes

    for (int t = 0; t < 1000; ++t) {
        u64* const scur = sbase + (size_t)(t & 1) * 1280;
        u64* const snxt = sbase + (size_t)((t + 1) & 1) * 1280;
        u64* const fcur = fbase + (size_t)(t & 1) * 1280;
        u64* const fnxt = fbase + (size_t)((t + 1) & 1) * 1280;

        // ---- spin: sc0 fast loads (L2) + agent fallback every 4th round ----
        u64 v0 = 0, v1 = 0, v2 = 0;
        bool g0 = false, g1 = false, g2 = !has3;
        const unsigned tg = (unsigned)t;
        int round = 0;
        for (;;) {
            u64 f0, f1, f2;
            asm volatile(
                "global_load_dwordx2 %0, %3, off sc0\n\t"
                "global_load_dwordx2 %1, %4, off sc0\n\t"
                "global_load_dwordx2 %2, %5, off sc0\n\t"
                "s_waitcnt vmcnt(0)"
                : "=&v"(f0), "=&v"(f1), "=&v"(f2)
                : "v"(fcur + e0), "v"(fcur + e1), "v"(fcur + e2)
                : "memory");
            if (!g0 && (unsigned)(f0 >> 32) == tg) { v0 = f0; g0 = true; }
            if (!g1 && (unsigned)(f1 >> 32) == tg) { v1 = f1; g1 = true; }
            if (!g2 && (unsigned)(f2 >> 32) == tg) { v2 = f2; g2 = true; }
            if (g0 & g1 & g2) break;
            if ((round & 3) == 2) {
                if (!g0) {
                    u64 s0 = __hip_atomic_load(&scur[e0], __ATOMIC_RELAXED, __HIP_MEMORY_SCOPE_AGENT);
                    if ((unsigned)(s0 >> 32) == tg) { v0 = s0; g0 = true; }
                }
                if (!g1) {
                    u64 s1 = __hip_atomic_load(&scur[e1], __ATOMIC_RELAXED, __HIP_MEMORY_SCOPE_AGENT);
                    if ((unsigned)(s1 >> 32) == tg) { v1 = s1; g1 = true; }
                }
                if (!g2) {
                    u64 s2 = __hip_atomic_load(&scur[e2], __ATOMIC_RELAXED, __HIP_MEMORY_SCOPE_AGENT);
                    if ((unsigned)(s2 >> 32) == tg) { v2 = s2; g2 = true; }
                }
                if (g0 & g1 & g2) break;
            }
            __builtin_amdgcn_s_sleep(1);
            ++round;
        }
        // ---- stage: entry e = kp*4 + b -> h_lds[b][kp] ----
        {
            union { unsigned u; h2v h; } pk;
            pk.u = (unsigned)v0; h_lds[(e0 & 3) * 324 + (e0 >> 2)] = pk.h;
            pk.u = (unsigned)v1; h_lds[(e1 & 3) * 324 + (e1 >> 2)] = pk.h;
            if (has3) { pk.u = (unsigned)v2; h_lds[(e2 & 3) * 324 + (e2 >> 2)] = pk.h; }
        }
        __syncthreads();   // S1: h staged

        // prefetch xp for t+1 (overlaps MFMA)
        float nxr = 0.f, nxz = 0.f, nxn = 0.f;
        if (t + 1 < 1000 && tid < 128) {
            int jg = sl * 32 + je;
            int bg = grp * 4 + be;
            const __half* xpt = xp + ((size_t)(t + 1) * 32 + bg) * 1920;
            nxr = __half2float(xpt[jg]);
            nxz = __half2float(xpt[640 + jg]);
            nxn = __half2float(xpt[1280 + jg]);
        }

        // ---- MFMA: 6 waves, 20 k-steps ----
        if (wid < 6) {
            int bb = lane & 15;
            int kq = lane >> 4;
            const h2v* hb = &h_lds[bb * 324 + kq * 4];
            f4 acc = {0.f, 0.f, 0.f, 0.f};
#pragma unroll
            for (int s = 0; s < 20; ++s) {
                half8 bfrag = *(const half8*)&hb[s * 16];
                acc = __builtin_amdgcn_mfma_f32_16x16x32_f16(afrag[s], bfrag, acc, 0, 0, 0);
            }
            if (bb < 4) {
#pragma unroll
                for (int i = 0; i < 4; ++i)
                    red[(bb * 33 + jt * 16 + kq * 4 + i) * 4 + gte] = acc[i];
            }
        }
        __syncthreads();   // S2: red ready

        // ---- epilogue: tid<128 = one (j,b) ----
        if (tid < 128) {
            f4 rv = *(const f4*)&red[(be * 33 + je) * 4];   // {r,z,n,pad}
            float hr = bh_r + rv.x;
            float hz = bh_z + rv.y;
            float hn = bh_n + rv.z;
            float r_ = 1.f / (1.f + __expf(-(xr + hr)));
            float z_ = 1.f / (1.f + __expf(-(xz + hz)));
            float pre = xn + r_ * hn;
            float e2v = __expf(-2.f * fabsf(pre));
            float tn = (1.f - e2v) / (1.f + e2v);
            float n_ = (pre >= 0.f) ? tn : -tn;
            float hnew = (1.f - z_) * n_ + z_ * hold;
            hold = hnew;
            // publish j-pair (even j holds {h[j], h[j+1]}); tid^4 = partner
            float hpair = __shfl_xor(hnew, 4);
            if ((je & 1) == 0) {
                union { h2v h2; unsigned u; } cv;
                cv.h2.x = (_Float16)hnew;
                cv.h2.y = (_Float16)hpair;
                u64 val = (u64)cv.u | ((u64)(unsigned)(t + 1) << 32);
                size_t eo = (size_t)((sl * 16 + (je >> 1)) * 4 + be);
                u64* fp = fnxt + eo;
                asm volatile("global_store_dwordx2 %0, %1, off sc0" :: "v"(fp), "v"(val) : "memory");
                (void)__hip_atomic_exchange(snxt + eo, val,
                                            __ATOMIC_RELAXED, __HIP_MEMORY_SCOPE_AGENT);
            }
            // fc partial: reduce over this wave's 16 j (b preserved by xor 4,8,16,32)
            float fv = hnew * fw;
            fv += __shfl_xor(fv, 4);
            fv += __shfl_xor(fv, 8);
            fv += __shfl_xor(fv, 16);
            fv += __shfl_xor(fv, 32);
            if (lane < 4) fcred[wid][lane] = fv;
        }
        xr = nxr; xz = nxz; xn = nxn;
        __syncthreads();   // S3: red/fcred consumed; h_lds free for next stage
        if (tid < 4)
            fcpart[(size_t)blk * 4000 + t * 4 + tid] = fcred[0][tid] + fcred[1][tid];
    }
}

// ---------------------------------------------------------------------------
// K9: final fc: out[b*1000+t] = fc_b + sum over the 20 j-slices of group b/4
__global__ void k_fc(const float* __restrict__ fcpart, const float* __restrict__ fcb,
                     float* __restrict__ out) {
    int gid = blockIdx.x * 256 + threadIdx.x;  // < 32000
    int t = gid >> 5;
    int b = gid & 31;
    int g = b >> 2, bi = b & 3;
    float s = fcb[0];
    for (int sl = 0; sl < 20; ++sl)
        s += fcpart[(size_t)(g + 8 * sl) * 4000 + t * 4 + bi];
    out[(size_t)b * 1000 + t] = s;
}

// ---------------------------------------------------------------------------
extern "C" void kernel_launch(void* const* d_in, const int* in_sizes, int n_in,
                              void* d_out, int out_size, void* d_ws, size_t ws_size,
                              hipStream_t stream) {
    const float* x      = (const float*)d_in[0];
    const float* a_vals = (const float*)d_in[1];
    const float* w_vals = (const float*)d_in[2];
    const float* dcls_w = (const float*)d_in[3];
    const float* dcls_p = (const float*)d_in[4];
    const float* dcls_b = (const float*)d_in[5];
    const float* gamma  = (const float*)d_in[6];
    const float* beta   = (const float*)d_in[7];
    const float* W_ih   = (const float*)d_in[8];
    const float* W_hh   = (const float*)d_in[9];
    const float* b_ih   = (const float*)d_in[10];
    const float* b_hh   = (const float*)d_in[11];
    const float* fc_w   = (const float*)d_in[12];
    const float* fc_b   = (const float*)d_in[13];
    char* w = (char*)d_ws;

    // ws layout (bytes). Peak total: ~164.0 MB.
    //   [0, 122,880,000)           xpH   fp16 32000x1920  -- phase D
    //       overlay [0, 81,920,000)        ybcgt fp32     -- phases A-B (dead before GEMM)
    //   [122,880,000, 163,840,000) seqH  fp16 32000x640   -- phases B-C
    //       overlay phase D: fcpart fp32 160x4000 at 122,880,000 (2.56MB);
    //                        fastb  u64 8grp x 2 x 1280 at 125,440,000 (164KB)
    //       overlay phase A: hp fp32 + dk fp32
    //   [163,840,000, 164,003,840) slowb u64 8grp x 2 x 1280 (agent-scope exchange)
    //   [164,003,840, 164,004,352) bnsum fp32 128
    //   [164,004,352, 164,004,864) bnp   fp32 128
    //   [164,004,864, 164,006,912) bar   u32 (legacy, unused)
    __half* xpH    = (__half*)(w);
    float* ybcgt   = (float*)(w);
    __half* seqH   = (__half*)(w + 122880000);
    float* hp      = (float*)(w + 122880000);
    float* dk      = (float*)(w + 122880000 + 4352000);
    float* fcpart  = (float*)(w + 122880000);
    u64* fastb     = (u64*)(w + 125440000);
    u64* slowb     = (u64*)(w + 163840000);
    float* bnsum   = (float*)(w + 164003840);

    // zero slow exchange buffers (tag 0 = h(-1)=0) + bn accumulators + bnp + bar
    hipMemsetAsync(w + 163840000, 0, 166912, stream);

    k_dk<<<dim3(315), dim3(256), 0, stream>>>(dcls_w, dcls_p, dk);
    k_ema<<<dim3(1088), dim3(256), 0, stream>>>(x, a_vals, w_vals, hp);
    k_conv<<<dim3(4, 10, 32), dim3(256), 0, stream>>>(hp, dk, dcls_b, ybcgt);
    k_bnstat<<<dim3(640), dim3(256), 0, stream>>>(ybcgt, bnsum);
    k_bnfin<<<dim3(1), dim3(64), 0, stream>>>(bnsum, gamma, beta, (float*)(w + 164004352));
    k_tr<<<dim3(16, 10, 32), dim3(256), 0, stream>>>(ybcgt, (float*)(w + 164004352), seqH);
    k_gemm<<<dim3(15, 250), dim3(256), 0, stream>>>(seqH, W_ih, b_ih, xpH);

    // fast exchange buffer overlays (now-dead) seqH bytes: zero AFTER k_gemm
    hipMemsetAsync(w + 125440000, 0, 163840, stream);

    {
        const __half* xp_a = xpH;
        void* args[] = {(void*)&xp_a, (void*)&W_hh, (void*)&b_hh, (void*)&fc_w,
                        (void*)&slowb, (void*)&fastb, (void*)&fcpart};
        hipLaunchCooperativeKernel((void*)k_gru, dim3(160), dim3(512), args, 0, stream);
    }

    k_fc<<<dim3(125), dim3(256), 0, stream>>>(fcpart, fc_b, (float*)d_out);
}